// Round 4
// baseline (4298.314 us; speedup 1.0000x reference)
//
#include <hip/hip_runtime.h>

#define NE 4096
#define BLK 256
#define MAXNUM 100

// |d|^2.4 = exp2(1.2*log2(d*d)); v_log_f32/v_exp_f32 are base-2.
__device__ __forceinline__ float pow24(float d) {
    float d2 = d * d;
    return __builtin_amdgcn_exp2f(1.2f * __builtin_amdgcn_logf(d2));
}

// inclusive scan over 64 lanes (Hillis-Steele)
__device__ __forceinline__ float wave_iscan(float v, int lane) {
#pragma unroll
    for (int off = 1; off < 64; off <<= 1) {
        float t = __shfl_up(v, off, 64);
        v += (lane >= off) ? t : 0.0f;
    }
    return v;
}
__device__ __forceinline__ float wave_reduce(float v) {
#pragma unroll
    for (int off = 1; off < 64; off <<= 1) v += __shfl_xor(v, off, 64);
    return v;
}

__global__ __launch_bounds__(BLK) void quant_kernel(const float* __restrict__ x,
                                                    float* __restrict__ out,
                                                    const int* __restrict__ nump) {
    const int c = blockIdx.x;
    const int tid = threadIdx.x;
    const int lane = tid & 63;
    const int wv = tid >> 6;
    int num = *nump;
    if (num > MAXNUM) num = MAXNUM;
    const int MAXM = 15 * num;

    __shared__ float sx[NE];
    __shared__ float SCint[MAXNUM * 16];   // interior band sums  (single writer/cell)
    __shared__ float SCup[MAXNUM * 16];    // upper-clamped sums  (single writer/cell)
    __shared__ float SCdn[MAXNUM * 16];    // lower-clamped sums  (single writer/cell)
    __shared__ unsigned short tposU[MAXNUM * 16];  // first e with r > j
    __shared__ unsigned short tposD[MAXNUM * 16];  // first e with r >= -j
    __shared__ unsigned short factab[15 * MAXNUM + 4];  // j-divisor mask per m
    __shared__ float csum0[65];
    __shared__ float rjl[16];
    __shared__ float redS[4];
    __shared__ int redI[4];

    const float* xrow = x + (size_t)c * NE;
    for (int idx = tid; idx < NE; idx += BLK) sx[idx] = xrow[idx];
    __syncthreads();

    // ---- bitonic ascending sort of the channel in LDS ----
    for (int kk = 2; kk <= NE; kk <<= 1) {
        for (int jj = kk >> 1; jj > 0; jj >>= 1) {
            for (int base = tid; base < NE; base += BLK) {
                int ixj = base ^ jj;
                if (ixj > base) {
                    float a = sx[base], b = sx[ixj];
                    if (((base & kk) == 0) ? (a > b) : (a < b)) { sx[base] = b; sx[ixj] = a; }
                }
            }
            __syncthreads();
        }
    }
    // sx sorted ascending, read-only from here.

    const float xmx = fmaxf(sx[NE - 1], 0.0f);
    const float xmn = fminf(sx[0], 0.0f);
    const float xrange = xmx - xmn;
    const float rdn = xrange / (float)num;   // matches ref: xrange/num then *i
    const float cfac = rdn / 15.0f;          // s_i*j ~= cfac*(i*j)

    // ---- phase 1: tables ----
    if (tid < 16) rjl[tid] = (tid >= 1) ? (1.0f / (float)tid) : 0.0f;
    for (int idx = tid; idx < num * 16; idx += BLK) {
        SCint[idx] = 0.0f; SCup[idx] = 0.0f; SCdn[idx] = 0.0f;
    }
    for (int m = tid; m <= MAXM; m += BLK) {
        unsigned int mask = 0;
#pragma unroll
        for (int j = 1; j <= 15; ++j)
            if (m >= j && (m % j) == 0 && (m / j) <= num) mask |= (1u << j);
        factab[m] = (unsigned short)mask;
    }
    // threshold binary searches: 2*num*16 cells, 13-step lower-bound
    for (int q = tid; q < 2 * num * 16; q += BLK) {
        int side = q >= num * 16;            // 0: up (r > j), 1: dn (r >= -j)
        int rem = side ? (q - num * 16) : q;
        int i1 = (rem >> 4) + 1;
        float jf = (float)(rem & 15);
        float tmp_max = rdn * (float)i1;
        float s = fmaxf(tmp_max / 15.0f, 1e-8f);
        float rs = 1.0f / s;
        int pos = 0;
#pragma unroll
        for (int st = 4096; st >= 1; st >>= 1) {
            if (pos + st <= NE) {
                float r = rintf(sx[pos + st - 1] * rs);
                bool pred = side ? (r >= -jf) : (r > jf);
                if (!pred) pos += st;
            }
        }
        if (side) tposD[rem] = (unsigned short)pos;
        else      tposU[rem] = (unsigned short)pos;
    }
    __syncthreads();

    // ---- phase 2a: interior band sums, wave-strided over i ----
    for (int i1 = wv + 1; i1 <= num; i1 += 4) {
        const float tmp_max = rdn * (float)i1;
        const float s = fmaxf(tmp_max / 15.0f, 1e-8f);
        const float rs = 1.0f / s;
        int mypos = -64;                      // lanes >= 32: never matches
        if (lane < 16) mypos = tposU[(i1 - 1) * 16 + lane];
        else if (lane < 32) mypos = tposD[(i1 - 1) * 16 + (lane - 16)];
        float Pval = 0.0f, running = 0.0f;
        for (int cc = 0; cc < 64; ++cc) {
            float xe = sx[(cc << 6) + lane];
            float r = rintf(xe * rs);
            float p = pow24(xe - s * r);      // two-step like reference
            float tot;
            if (__ballot((mypos >> 6) == cc)) {
                float v = wave_iscan(p, lane);
                tot = __shfl(v, 63, 64);
                int lp = mypos & 63;
                float pref = __shfl(v, (lp - 1) & 63, 64);
                if ((mypos >> 6) == cc) Pval = running + ((lp != 0) ? pref : 0.0f);
            } else {
                tot = wave_reduce(p);
            }
            running += tot;
        }
        if (mypos == NE) Pval = running;      // prefix over everything
        // SCint[i][z] = PreIn(t_up[15-z]) - PreIn(t_dn[z])
        float pa = __shfl(Pval, (15 - lane) & 63, 64);
        float pb = __shfl(Pval, (lane + 16) & 63, 64);
        if (lane < 16) SCint[(i1 - 1) * 16 + lane] = pa - pb;
    }

    // ---- phase 2b: m = 0 (j=0 terms, p(x) itself) — wave 0 ----
    if (wv == 0) {
        float running = 0.0f;
        for (int cc = 0; cc < 64; ++cc) {
            float p = pow24(sx[(cc << 6) + lane]);
            float tot = wave_reduce(p);
            if (lane == 0) csum0[cc] = running;
            running += tot;
        }
        if (lane == 0) csum0[64] = running;
        __threadfence_block();
        const float tot0 = running;
#pragma unroll
        for (int b = 0; b < 4; ++b) {
            int fid = (b << 6) + lane;        // up facts [0,num), dn facts [num,2num)
            if (fid < 2 * num) {
                int side = fid >= num;
                int i1 = (side ? (fid - num) : fid) + 1;
                int tp = side ? tposD[(i1 - 1) * 16] : tposU[(i1 - 1) * 16];
                int cc6 = tp >> 6, lp = tp & 63;   // tp==4096 -> csum0[64]=total, lp=0
                float pre = csum0[cc6];
                for (int k2 = 0; k2 < lp; ++k2) pre += pow24(sx[(cc6 << 6) + k2]);
                if (side) SCdn[(i1 - 1) * 16 + 0] = pre;
                else      SCup[(i1 - 1) * 16 + 15] = tot0 - pre;
            }
        }
    }

    // ---- phase 2c: shared-product passes, m >= 1, wave-strided ----
    for (int m = (wv == 0 ? 4 : wv); m <= MAXM; m += 4) {
        const unsigned int mask0 = factab[m];
        if (mask0 == 0) continue;
        const float wm = cfac * (float)m;
        // ---- UP: suffix sums of p(x - wm), descending chunks ----
        {
            unsigned int rm = mask0;
            int cmin = 64, ntp = -1, nj = 0, ni1 = 0;
            unsigned int t = mask0;
            while (t) {
                int j = __ffs(t) - 1; t &= (t - 1);
                int i1 = (int)rintf((float)m * rjl[j]);
                int tp = tposU[(i1 - 1) * 16 + j];
                if (tp < NE) {
                    int ch = tp >> 6;
                    if (ch < cmin) cmin = ch;
                    if (tp > ntp) { ntp = tp; nj = j; ni1 = i1; }
                }
            }
            if (ntp >= 0) {
                float running = 0.0f;
                for (int cc = 63; cc >= cmin; --cc) {
                    float p = pow24(sx[(cc << 6) + lane] - wm);
                    float tot, v = 0.0f;
                    bool doscan = (ntp >= 0) && ((ntp >> 6) == cc);
                    if (doscan) { v = wave_iscan(p, lane); tot = __shfl(v, 63, 64); }
                    else tot = wave_reduce(p);
                    while (ntp >= 0 && (ntp >> 6) == cc) {
                        int lp = ntp & 63;
                        float pref = __shfl(v, (lp - 1) & 63, 64);
                        float snap = running + (tot - ((lp != 0) ? pref : 0.0f));
                        if (lane == 0) SCup[(ni1 - 1) * 16 + (15 - nj)] = snap;
                        rm &= ~(1u << nj);
                        ntp = -1;
                        unsigned int t2 = rm;
                        while (t2) {
                            int j2 = __ffs(t2) - 1; t2 &= (t2 - 1);
                            int i2 = (int)rintf((float)m * rjl[j2]);
                            int tp2 = tposU[(i2 - 1) * 16 + j2];
                            if (tp2 < NE && tp2 > ntp) { ntp = tp2; nj = j2; ni1 = i2; }
                        }
                    }
                    running += tot;
                }
            }
        }
        // ---- DN: prefix sums of p(x + wm), ascending chunks ----
        {
            unsigned int rm = mask0;
            int cmax = -1, ntp = 1 << 30, nj = 0, ni1 = 0;
            unsigned int t = mask0;
            while (t) {
                int j = __ffs(t) - 1; t &= (t - 1);
                int i1 = (int)rintf((float)m * rjl[j]);
                int tp = tposD[(i1 - 1) * 16 + j];
                if (tp > 0) {
                    int ch = (tp >= NE) ? 63 : (tp >> 6);
                    if (ch > cmax) cmax = ch;
                    if (tp < ntp) { ntp = tp; nj = j; ni1 = i1; }
                }
            }
            if (cmax >= 0) {
                float running = 0.0f;
                for (int cc = 0; cc <= cmax; ++cc) {
                    float p = pow24(sx[(cc << 6) + lane] + wm);
                    float tot, v = 0.0f;
                    bool doscan = (ntp < NE) && ((ntp >> 6) == cc);
                    if (doscan) { v = wave_iscan(p, lane); tot = __shfl(v, 63, 64); }
                    else tot = wave_reduce(p);
                    while (ntp < NE && (ntp >> 6) == cc) {
                        int lp = ntp & 63;
                        float pref = __shfl(v, (lp - 1) & 63, 64);
                        float snap = running + ((lp != 0) ? pref : 0.0f);
                        if (lane == 0) SCdn[(ni1 - 1) * 16 + nj] = snap;
                        rm &= ~(1u << nj);
                        ntp = 1 << 30;
                        unsigned int t2 = rm;
                        while (t2) {
                            int j2 = __ffs(t2) - 1; t2 &= (t2 - 1);
                            int i2 = (int)rintf((float)m * rjl[j2]);
                            int tp2 = tposD[(i2 - 1) * 16 + j2];
                            if (tp2 > 0 && tp2 < ntp) { ntp = tp2; nj = j2; ni1 = i2; }
                        }
                    }
                    running += tot;
                }
                // leftovers: tp == 4096 (everything lower-clamped) -> full total
                while (ntp != (1 << 30)) {
                    if (lane == 0) SCdn[(ni1 - 1) * 16 + nj] = running;
                    rm &= ~(1u << nj);
                    ntp = 1 << 30;
                    unsigned int t2 = rm;
                    while (t2) {
                        int j2 = __ffs(t2) - 1; t2 &= (t2 - 1);
                        int i2 = (int)rintf((float)m * rjl[j2]);
                        int tp2 = tposD[(i2 - 1) * 16 + j2];
                        if (tp2 > 0 && tp2 < ntp) { ntp = tp2; nj = j2; ni1 = i2; }
                    }
                }
            }
        }
    }

    // ---- phase 3: lex-min over (score, i, z); flat idx order == ref tie order ----
    __syncthreads();
    float bsc = 3.4e38f;
    int bidx = 1 << 30;
    for (int idx = tid; idx < num * 16; idx += BLK) {
        float sc = SCint[idx] + (SCup[idx] + SCdn[idx]);
        if (sc < bsc || (sc == bsc && idx < bidx)) { bsc = sc; bidx = idx; }
    }
#pragma unroll
    for (int k2 = 1; k2 < 64; k2 <<= 1) {
        float os = __shfl_xor(bsc, k2, 64);
        int oi = __shfl_xor(bidx, k2, 64);
        if (os < bsc || (os == bsc && oi < bidx)) { bsc = os; bidx = oi; }
    }
    if (lane == 0) { redS[wv] = bsc; redI[wv] = bidx; }
    __syncthreads();
    bsc = redS[0]; bidx = redI[0];
#pragma unroll
    for (int w2 = 1; w2 < 4; ++w2) {
        float os = redS[w2]; int oi = redI[w2];
        if (os < bsc || (os == bsc && oi < bidx)) { bsc = os; bidx = oi; }
    }
    const int besti = (bidx >> 4) + 1;
    const float bzf = (float)(bidx & 15);
    const float tmpb = rdn * (float)besti;
    const float sb = fmaxf(tmpb / 15.0f, 1e-8f);
    const float zs = bzf * sb;
    const float min_neg = fminf(-zs, 0.0f);
    const float max_pos = fmaxf(tmpb - zs, 0.0f);
    const float scale = fmaxf((max_pos - min_neg) / 15.0f, 1e-8f);
    const float zero = fminf(fmaxf(0.0f - rintf(min_neg / scale), 0.0f), 15.0f);

    float* orow = out + (size_t)c * NE;
    for (int idx = tid; idx < NE; idx += BLK) {
        float xe = xrow[idx];
        float q = fminf(fmaxf(rintf(xe / scale) + zero, 0.0f), 15.0f);
        orow[idx] = scale * (q - zero);
    }
}

extern "C" void kernel_launch(void* const* d_in, const int* in_sizes, int n_in,
                              void* d_out, int out_size, void* d_ws, size_t ws_size,
                              hipStream_t stream) {
    const float* x = (const float*)d_in[0];
    const int* nump = (const int*)d_in[1];
    float* out = (float*)d_out;
    const int C = out_size / NE;
    quant_kernel<<<C, BLK, 0, stream>>>(x, out, nump);
}

// Round 5
// 1163.312 us; speedup vs baseline: 3.6949x; 3.6949x over previous
//
#include <hip/hip_runtime.h>

#define NE 4096
#define BLK 512
#define NWAVE (BLK / 64)

// |d|^2.4 = exp2(1.2*log2(d*d)); v_log_f32/v_exp_f32 are base-2.
__device__ __forceinline__ float pow24(float d) {
    float d2 = d * d;
    return __builtin_amdgcn_exp2f(1.2f * __builtin_amdgcn_logf(d2));
}

__global__ __launch_bounds__(BLK) void quant_kernel(const float* __restrict__ x,
                                                    float* __restrict__ out,
                                                    const int* __restrict__ nump) {
    const int c = blockIdx.x;
    const int tid = threadIdx.x;
    const int lane = tid & 63;
    const int wv = tid >> 6;
    const int num = *nump;

    __shared__ float sx[NE];
    __shared__ float fsc[NWAVE], ffi[NWAVE], fmn[NWAVE], fmx[NWAVE];

    const float* xrow = x + (size_t)c * NE;
    for (int idx = tid; idx < NE; idx += BLK) sx[idx] = xrow[idx];
    __syncthreads();

    // ---- bitonic ascending sort of the channel in LDS (once) ----
    for (int k = 2; k <= NE; k <<= 1) {
        for (int j = k >> 1; j > 0; j >>= 1) {
            for (int base = tid; base < NE; base += BLK) {
                int ixj = base ^ j;
                if (ixj > base) {
                    float a = sx[base], b = sx[ixj];
                    if (((base & k) == 0) ? (a > b) : (a < b)) { sx[base] = b; sx[ixj] = a; }
                }
            }
            __syncthreads();
        }
    }
    // sx sorted ascending, read-only from here.

    const float xmn = fminf(sx[0], 0.0f);
    const float xmx = fmaxf(sx[NE - 1], 0.0f);
    const float xrange = xmx - xmn;
    const float rdn = xrange / (float)num;  // matches ref: xrange/num then *i

    // z held by this lane after the value-halving butterfly: bitrev4(lane&15)
    const int zmy = ((lane & 1) << 3) | ((lane & 2) << 1) | ((lane & 4) >> 1) | ((lane & 8) >> 3);
    const float zmyf = (float)zmy;

    float best_score = 1e10f;
    float best_fi = 1e9f;
    float best_min = xmn, best_max = xmx;

    // each wave owns a strided 1/8 of the i-range; no barriers in this loop
    for (int i = wv + 1; i <= num; i += NWAVE) {
        const float fi = (float)i;
        const float tmp_max = rdn * fi;
        const float s = fmaxf(tmp_max / 15.0f, 1e-8f);  // exact div, uniform
        const float ns = -s;
        const float rs = 1.0f / s;                       // exact div, uniform

        float tacc = 0.0f;   // sum of interior residuals (z-independent part)
        float corr[16];      // per-z clamped corrections
#pragma unroll
        for (int z = 0; z < 16; ++z) corr[z] = 0.0f;

        for (int cc = 0; cc < 64; ++cc) {
            const float xe = sx[(cc << 6) + lane];       // sorted slice
            const float r = rintf(xe * rs);              // integer-valued float
            const float p_in = pow24(fmaf(ns, r, xe));
            tacc += p_in;

            // wave-uniform clamp counts from slice extremes (lane0=min, lane63=max)
            const float rmaxw = __int_as_float(__builtin_amdgcn_readlane(__float_as_int(r), 63));
            const float rminw = __int_as_float(__builtin_amdgcn_readlane(__float_as_int(r), 0));
            const int nhi = (int)fminf(fmaxf(rmaxw, 0.0f), 16.0f);
            const int nlo = (int)fminf(fmaxf(-rminw, 0.0f), 16.0f);

            // upper-clamped: z = 15-j, active iff r > j, d = xe - s*j
#pragma unroll
            for (int j = 0; j < 16; ++j) {
                if (j >= nhi) break;                     // uniform (SGPR) break
                const float jf = (float)j;
                const float ph = pow24(fmaf(ns, jf, xe));
                corr[15 - j] += (r > jf) ? (ph - p_in) : 0.0f;
            }
            // lower-clamped: z = j, active iff r < -j, d = xe + s*j
#pragma unroll
            for (int j = 0; j < 16; ++j) {
                if (j >= nlo) break;
                const float jf = (float)j;
                const float pl = pow24(fmaf(s, jf, xe));
                corr[j] += (r < -jf) ? (pl - p_in) : 0.0f;
            }
        }

        // ---- full-wave butterfly on tacc (identical value on all lanes) ----
#pragma unroll
        for (int k = 1; k < 64; k <<= 1) tacc += __shfl_xor(tacc, k, 64);

        // ---- in-register value-halving butterfly: 16 corrs over 64 lanes ----
#pragma unroll
        for (int q = 0; q < 8; ++q) {
            float send = (lane & 1) ? corr[q] : corr[q + 8];
            float keep = (lane & 1) ? corr[q + 8] : corr[q];
            corr[q] = keep + __shfl_xor(send, 1, 64);
        }
#pragma unroll
        for (int q = 0; q < 4; ++q) {
            float send = (lane & 2) ? corr[q] : corr[q + 4];
            float keep = (lane & 2) ? corr[q + 4] : corr[q];
            corr[q] = keep + __shfl_xor(send, 2, 64);
        }
#pragma unroll
        for (int q = 0; q < 2; ++q) {
            float send = (lane & 4) ? corr[q] : corr[q + 2];
            float keep = (lane & 4) ? corr[q + 2] : corr[q];
            corr[q] = keep + __shfl_xor(send, 4, 64);
        }
        {
            float send = (lane & 8) ? corr[0] : corr[1];
            float keep = (lane & 8) ? corr[1] : corr[0];
            corr[0] = keep + __shfl_xor(send, 8, 64);
        }
        corr[0] += __shfl_xor(corr[0], 16, 64);
        corr[0] += __shfl_xor(corr[0], 32, 64);
        float sc = (tacc + corr[0]) * (1.0f / 4096.0f);  // mean = sum * 2^-12

        // lex argmin over z (tie -> smaller z), result uniform across wave
        float bsz = sc, bzz = zmyf;
#pragma unroll
        for (int k = 1; k < 64; k <<= 1) {
            float os = __shfl_xor(bsz, k, 64);
            float oz = __shfl_xor(bzz, k, 64);
            bool take = (os < bsz) || ((os == bsz) && (oz < bzz));
            bsz = take ? os : bsz;
            bzz = take ? oz : bzz;
        }
        if (bsz < best_score) {                          // strict <, ascending i per wave
            best_score = bsz;
            best_fi = fi;
            float zs = bzz * s;
            best_min = -zs;                              // new_min = -zbest*delta
            best_max = tmp_max - zs;                     // new_max = tmp_max - zbest*delta
        }
    }

    // ---- cross-wave lex-min on (score, i): matches sequential strict-< semantics ----
    if (lane == 0) { fsc[wv] = best_score; ffi[wv] = best_fi; fmn[wv] = best_min; fmx[wv] = best_max; }
    __syncthreads();
    float bs = fsc[0], bi = ffi[0], bm = fmn[0], bxv = fmx[0];
#pragma unroll
    for (int w = 1; w < NWAVE; ++w) {
        bool take = (fsc[w] < bs) || ((fsc[w] == bs) && (ffi[w] < bi));
        if (take) { bs = fsc[w]; bi = ffi[w]; bm = fmn[w]; bxv = fmx[w]; }
    }

    const float min_neg = fminf(bm, 0.0f);
    const float max_pos = fmaxf(bxv, 0.0f);
    const float scale = fmaxf((max_pos - min_neg) / 15.0f, 1e-8f);
    const float zero = fminf(fmaxf(0.0f - rintf(min_neg / scale), 0.0f), 15.0f);

    float* orow = out + (size_t)c * NE;
    for (int idx = tid; idx < NE; idx += BLK) {
        float xe = xrow[idx];                            // original order, exact div
        float q = fminf(fmaxf(rintf(xe / scale) + zero, 0.0f), 15.0f);
        orow[idx] = scale * (q - zero);
    }
}

extern "C" void kernel_launch(void* const* d_in, const int* in_sizes, int n_in,
                              void* d_out, int out_size, void* d_ws, size_t ws_size,
                              hipStream_t stream) {
    const float* x = (const float*)d_in[0];
    const int* nump = (const int*)d_in[1];
    float* out = (float*)d_out;
    const int C = out_size / NE;
    quant_kernel<<<C, BLK, 0, stream>>>(x, out, nump);
}